// Round 20
// baseline (121.029 us; speedup 1.0000x reference)
//
#include <hip/hip_runtime.h>

// Problem constants (fixed by the reference).
constexpr int IN_CH = 4;
constexpr int KS    = 40;
constexpr int L_IN  = 8192;
constexpr int L_OUT = L_IN - KS + 1;   // 8153
constexpr int NF    = 600;
constexpr int BATCH = 32;
constexpr int SLEN  = 512;             // sixteenth length (64B multiple); last = 473
constexpr int RPX   = NF * BATCH / 8;  // 2400 rows per XCD slice

typedef float floatx4  __attribute__((ext_vector_type(4)));                 // 16B-aligned (stores)
typedef float floatx4u __attribute__((ext_vector_type(4), aligned(4)));     // 4B-aligned (reads)

// R20 = R19 (112.2us best) next granularity rung: sixteenth-row spans,
// 128-thread blocks (307200 blocks, one float4 per thread, 2 waves/block).
// idx>>4 = row-in-slice, idx&15 = sixteenth -> per-XCD walk sequential.
// Ladder: 19200=124.8, 38400=122.4, 76800=119.7, 153600=112.2 us.
__global__ __launch_bounds__(128) void fdc_sixt(const float* __restrict__ x,
                                                const float* __restrict__ w,
                                                float* __restrict__ out) {
    const int bid  = blockIdx.x;            // 0..307199
    const int xcd  = bid & 7;
    const int idx  = bid >> 3;              // 0..38399, sequential within XCD
    const int sixt = idx & 15;
    const int row  = xcd * RPX + (idx >> 4);
    const int b    = row / NF;
    const int k    = row - b * NF;

    // ---- per-block tap extraction (both waves redundant; uniform result) ----
    const float* wk  = w + (size_t)k * IN_CH * KS;   // 160 floats
    const int    lane = threadIdx.x & 63;
    const float  a0 = wk[lane];
    const float  a1 = wk[lane + 64];
    const float  a2 = (lane < 32) ? wk[lane + 128] : 0.0f;   // guard k=599 OOB
    const unsigned long long m0 = __ballot(a0 != 0.0f);
    const unsigned long long m1 = __ballot(a1 != 0.0f);
    const unsigned long long m2 = __ballot(a2 != 0.0f);
    int i0, i1;
    if (m0)      i0 = __builtin_ctzll(m0);
    else if (m1) i0 = 64 + __builtin_ctzll(m1);
    else         i0 = 128 + __builtin_ctzll(m2);
    if (m2)      i1 = 128 + 63 - __builtin_clzll(m2);
    else if (m1) i1 = 64 + 63 - __builtin_clzll(m1);
    else         i1 = 63 - __builtin_clzll(m0);
    const float w0 = wk[i0];                          // uniform scalar loads
    const float w1 = wk[i1];

    const int off = sixt * SLEN;
    const int len = (sixt == 15) ? (L_OUT - 15 * SLEN) : SLEN;

    const float* xb = x + (size_t)b * IN_CH * L_IN;
    const float* x0 = xb + (i0 / KS) * L_IN + (i0 % KS) + off;
    const float* x1 = xb + (i1 / KS) * L_IN + (i1 % KS) + off;

    const size_t s0   = (size_t)row * L_OUT + off;    // element offset of span
    float*       orow = out + s0;
    const int    a    = (int)((0u - (unsigned)s0) & 15u);  // head elems to 64B boundary
    const int    n4   = (len - a) >> 2;                    // aligned float4s (<=128)
    const int    tail = len - a - (n4 << 2);               // <= 3

    const int t = threadIdx.x;
    if (t < n4) {                                          // exactly one float4/thread
        const int l = a + t * 4;
        const floatx4u v0 = *reinterpret_cast<const floatx4u*>(x0 + l);
        const floatx4u v1 = *reinterpret_cast<const floatx4u*>(x1 + l);
        floatx4 v;
        v.x = w0 * v0.x + w1 * v1.x;
        v.y = w0 * v0.y + w1 * v1.y;
        v.z = w0 * v0.z + w1 * v1.z;
        v.w = w0 * v0.w + w1 * v1.w;
        __builtin_nontemporal_store(v, reinterpret_cast<floatx4*>(orow + l));
    }

    // head [0,a) + tail [a+4*n4, len): <= 18 scalars, lanes 104..127
    const unsigned hidx = (unsigned)t - 104u;
    if (hidx < 24u) {
        int elem = -1;
        if ((int)hidx < a) {
            elem = (int)hidx;
        } else {
            const int rr = (int)hidx - a;
            if (rr < tail) elem = a + (n4 << 2) + rr;
        }
        if (elem >= 0) orow[elem] = w0 * x0[elem] + w1 * x1[elem];
    }
}

extern "C" void kernel_launch(void* const* d_in, const int* in_sizes, int n_in,
                              void* d_out, int out_size, void* d_ws, size_t ws_size,
                              hipStream_t stream) {
    const float* x = (const float*)d_in[0];   // [32, 4, 8192] fp32
    const float* w = (const float*)d_in[1];   // [600, 4, 40]  fp32
    float*       o = (float*)d_out;           // [32, 600, 8153] fp32
    (void)d_ws; (void)ws_size;

    fdc_sixt<<<NF * BATCH * 16, 128, 0, stream>>>(x, w, o);   // 307200 sixteenth-row blocks
}

// Round 21
// 112.011 us; speedup vs baseline: 1.0805x; 1.0805x over previous
//
#include <hip/hip_runtime.h>

// Problem constants (fixed by the reference).
constexpr int IN_CH = 4;
constexpr int KS    = 40;
constexpr int L_IN  = 8192;
constexpr int L_OUT = L_IN - KS + 1;   // 8153
constexpr int NF    = 600;
constexpr int BATCH = 32;
constexpr int ELEN  = 1024;            // eighth length (64B multiple); last = 985
constexpr int RPX   = NF * BATCH / 8;  // 2400 rows per XCD slice

typedef float floatx4  __attribute__((ext_vector_type(4)));                 // 16B-aligned (stores)
typedef float floatx4u __attribute__((ext_vector_type(4), aligned(4)));     // 4B-aligned (reads)

// FINAL (= R19, measured 112.2us): eighth-row blocks (153600), 256 threads,
// exactly one float4 store per thread. Granularity ladder peak: 19200=124.8,
// 38400=122.4, 76800=119.7, 153600=112.2, 307200(128t)=121.0 us.
// Levers banked: single fused dispatch (-24us), NT stores (-16us x2),
// XCD-sequential swizzle (-15us), direct-L2 reads (-11us), granularity
// (-12.6us). Falsified: store width, read volume, stream consolidation x2,
// deep unroll, plain stores x2, low-occupancy tiling, sub-wave granularity.
__global__ __launch_bounds__(256) void fdc_eighth(const float* __restrict__ x,
                                                  const float* __restrict__ w,
                                                  float* __restrict__ out) {
    const int bid    = blockIdx.x;          // 0..153599
    const int xcd    = bid & 7;
    const int idx    = bid >> 3;            // 0..19199, sequential within XCD
    const int eighth = idx & 7;
    const int row    = xcd * RPX + (idx >> 3);
    const int b      = row / NF;
    const int k      = row - b * NF;

    // ---- per-block tap extraction (all waves redundant; uniform result) ----
    const float* wk  = w + (size_t)k * IN_CH * KS;   // 160 floats
    const int    lane = threadIdx.x & 63;
    const float  a0 = wk[lane];
    const float  a1 = wk[lane + 64];
    const float  a2 = (lane < 32) ? wk[lane + 128] : 0.0f;   // guard k=599 OOB
    const unsigned long long m0 = __ballot(a0 != 0.0f);
    const unsigned long long m1 = __ballot(a1 != 0.0f);
    const unsigned long long m2 = __ballot(a2 != 0.0f);
    int i0, i1;
    if (m0)      i0 = __builtin_ctzll(m0);
    else if (m1) i0 = 64 + __builtin_ctzll(m1);
    else         i0 = 128 + __builtin_ctzll(m2);
    if (m2)      i1 = 128 + 63 - __builtin_clzll(m2);
    else if (m1) i1 = 64 + 63 - __builtin_clzll(m1);
    else         i1 = 63 - __builtin_clzll(m0);
    const float w0 = wk[i0];                          // uniform scalar loads
    const float w1 = wk[i1];

    const int off = eighth * ELEN;
    const int len = (eighth == 7) ? (L_OUT - 7 * ELEN) : ELEN;

    const float* xb = x + (size_t)b * IN_CH * L_IN;
    const float* x0 = xb + (i0 / KS) * L_IN + (i0 % KS) + off;
    const float* x1 = xb + (i1 / KS) * L_IN + (i1 % KS) + off;

    const size_t s0   = (size_t)row * L_OUT + off;    // element offset of span
    float*       orow = out + s0;
    const int    a    = (int)((0u - (unsigned)s0) & 15u);  // head elems to 64B boundary
    const int    n4   = (len - a) >> 2;                    // aligned float4s (<=256)
    const int    tail = len - a - (n4 << 2);               // <= 3

    const int t = threadIdx.x;
    if (t < n4) {                                          // exactly one float4/thread
        const int l = a + t * 4;
        const floatx4u v0 = *reinterpret_cast<const floatx4u*>(x0 + l);
        const floatx4u v1 = *reinterpret_cast<const floatx4u*>(x1 + l);
        floatx4 v;
        v.x = w0 * v0.x + w1 * v1.x;
        v.y = w0 * v0.y + w1 * v1.y;
        v.z = w0 * v0.z + w1 * v1.z;
        v.w = w0 * v0.w + w1 * v1.w;
        __builtin_nontemporal_store(v, reinterpret_cast<floatx4*>(orow + l));
    }

    // head [0,a) + tail [a+4*n4, len): <= 18 scalars, lanes 232..255
    const unsigned hidx = (unsigned)t - 232u;
    if (hidx < 24u) {
        int elem = -1;
        if ((int)hidx < a) {
            elem = (int)hidx;
        } else {
            const int rr = (int)hidx - a;
            if (rr < tail) elem = a + (n4 << 2) + rr;
        }
        if (elem >= 0) orow[elem] = w0 * x0[elem] + w1 * x1[elem];
    }
}

extern "C" void kernel_launch(void* const* d_in, const int* in_sizes, int n_in,
                              void* d_out, int out_size, void* d_ws, size_t ws_size,
                              hipStream_t stream) {
    const float* x = (const float*)d_in[0];   // [32, 4, 8192] fp32
    const float* w = (const float*)d_in[1];   // [600, 4, 40]  fp32
    float*       o = (float*)d_out;           // [32, 600, 8153] fp32
    (void)d_ws; (void)ws_size;

    fdc_eighth<<<NF * BATCH * 8, 256, 0, stream>>>(x, w, o);   // 153600 eighth-row blocks
}